// Round 2
// 834.930 us; speedup vs baseline: 1.0314x; 1.0314x over previous
//
#include <hip/hip_runtime.h>

#define S 2048
#define D 64
#define BH 32
#define CHUNK 128
#define NCH (S / CHUNK)
#define MTILE 64

typedef __attribute__((ext_vector_type(8))) short bfrag;
typedef __attribute__((ext_vector_type(4))) float f32x4;

__device__ __forceinline__ unsigned short f2bf(float f) {
    unsigned int u = __builtin_bit_cast(unsigned int, f);
    u += 0x7fffu + ((u >> 16) & 1u);
    return (unsigned short)(u >> 16);
}
__device__ __forceinline__ ushort4 f2bf4(float4 f) {
    ushort4 u;
    u.x = f2bf(f.x); u.y = f2bf(f.y); u.z = f2bf(f.z); u.w = f2bf(f.w);
    return u;
}

// Detect mask storage: int32 0/1 (first 1024 words all <=1) vs packed bytes.
__global__ void mask_detect_kernel(const unsigned int* __restrict__ m, int* __restrict__ flag) {
    __shared__ int any;
    if (threadIdx.x == 0) any = 0;
    __syncthreads();
    unsigned int v0 = m[threadIdx.x];
    unsigned int v1 = m[threadIdx.x + 256];
    unsigned int v2 = m[threadIdx.x + 512];
    unsigned int v3 = m[threadIdx.x + 768];
    if (v0 > 1u || v1 > 1u || v2 > 1u || v3 > 1u) any = 1;
    __syncthreads();
    if (threadIdx.x == 0) *flag = any;  // 1 => byte mask, 0 => int32 mask
}

// Stage 64x128 mask tile as bits: Msb[row][word], word w covers cols w*32..w*32+31.
__device__ __forceinline__ void stage_mask_bits(unsigned int (*Msb)[5],
                                                const unsigned char* __restrict__ mb,
                                                const int* __restrict__ mi,
                                                int bytemode, int t, int r0, int j0) {
    const int r2 = t >> 2, wq = t & 3;
    unsigned mword = 0;
    if (bytemode) {
        const unsigned char* sm = &mb[(size_t)(r0 + r2) * S + j0 + wq * 32];
#pragma unroll
        for (int i = 0; i < 8; ++i) {
            unsigned u = *(const unsigned int*)&sm[i * 4] & 0x01010101u;
            unsigned nib = (u | (u >> 7) | (u >> 14) | (u >> 21)) & 0xFu;
            mword |= nib << (i * 4);
        }
    } else {
        const int* sm = &mi[(size_t)(r0 + r2) * S + j0 + wq * 32];
#pragma unroll
        for (int i = 0; i < 8; ++i) {
            int4 w = *(const int4*)&sm[i * 4];
            unsigned nib = (unsigned)(w.x & 1) | ((unsigned)(w.y & 1) << 1) |
                           ((unsigned)(w.z & 1) << 2) | ((unsigned)(w.w & 1) << 3);
            mword |= nib << (i * 4);
        }
    }
    Msb[r2][wq] = mword;
}

__global__ __launch_bounds__(256, 4)
void attn_mfma_kernel(const float* __restrict__ q, const float* __restrict__ k,
                      const float* __restrict__ v,
                      const int* __restrict__ mask_i, const unsigned char* __restrict__ mask_b,
                      const int* __restrict__ flag,
                      float* __restrict__ out, float* __restrict__ atten) {
    // KsPs: K tile [128][72] shorts; after QK^T (extra barrier) the SAME space holds
    //       wave-private P: base wv*2176, stride 136 shorts per row.
    __shared__ __attribute__((aligned(16))) unsigned short KsPs[128 * 72];  // 18432 B
    // Vt: V^T [64 d][136 r] shorts, write-swizzled (r ^= c&32) for conflict-free staging.
    //     In Phase B it is reused as wave-private f32 transpose buf [4][16][68].
    __shared__ __attribute__((aligned(16))) unsigned short Vt[64 * 136];    // 17408 B
    __shared__ unsigned int Msb[64][5];                                     //  1280 B
    // total 37120 B -> 4 blocks/CU

    const int t    = threadIdx.x;
    const int lane = t & 63;
    const int wv   = t >> 6;        // wave 0..3, owns q-rows wv*16..+15
    const int quad = lane >> 4;     // 0..3
    const int l16  = lane & 15;
    const int bh   = blockIdx.y;    // 0..31
    const int r0   = blockIdx.x * MTILE;
    const int bz   = bh >> 4;       // batch (H=16)

    const float* kb = k + (size_t)bh * S * D;
    const float* vb = v + (size_t)bh * S * D;
    const unsigned char* mb = mask_b + (size_t)bz * S * S;
    const int*           mi = mask_i + (size_t)bz * S * S;
    const int bytemode = *flag;

    // ---- Q fragments straight to registers, pre-scaled by 1/sqrt(64) ----
    bfrag qf[2];
    {
        const float* qrow = q + ((size_t)bh * S + r0 + wv * 16 + l16) * D + quad * 8;
#pragma unroll
        for (int ks = 0; ks < 2; ++ks) {
            float4 a = *(const float4*)&qrow[ks * 32];
            float4 b = *(const float4*)&qrow[ks * 32 + 4];
            a.x *= 0.125f; a.y *= 0.125f; a.z *= 0.125f; a.w *= 0.125f;
            b.x *= 0.125f; b.y *= 0.125f; b.z *= 0.125f; b.w *= 0.125f;
            union { bfrag f; ushort4 h[2]; } u;
            u.h[0] = f2bf4(a);
            u.h[1] = f2bf4(b);
            qf[ks] = u.f;
        }
    }

    float lsum[4] = {0.f, 0.f, 0.f, 0.f};
    f32x4 acc_o[4];
#pragma unroll
    for (int n = 0; n < 4; ++n) acc_o[n] = (f32x4){0.f, 0.f, 0.f, 0.f};

    const int psb = wv * 2176;  // P base in KsPs (shorts)

    // =================== Phase A: row sums + O = P·V ===================
    for (int ch = 0; ch < NCH; ++ch) {
        const int j0 = ch * CHUNK;
        __syncthreads();  // previous chunk fully consumed
        {   // stage K (row-major bf16) and V (transposed bf16, write-swizzled) + mask bits
            const int r = t >> 1, c0 = (t & 1) * 32;
            const int rsw = r ^ ((t & 1) << 5);   // V write swizzle: col-half XORs row bit5
            const float* sk = &kb[(size_t)(j0 + r) * D + c0];
            const float* sv = &vb[(size_t)(j0 + r) * D + c0];
#pragma unroll
            for (int i = 0; i < 8; ++i) {
                float4 f = *(const float4*)&sk[i * 4];
                *(ushort4*)&KsPs[r * 72 + c0 + i * 4] = f2bf4(f);
            }
#pragma unroll
            for (int i = 0; i < 8; ++i) {
                float4 f = *(const float4*)&sv[i * 4];
                Vt[(c0 + i * 4 + 0) * 136 + rsw] = f2bf(f.x);
                Vt[(c0 + i * 4 + 1) * 136 + rsw] = f2bf(f.y);
                Vt[(c0 + i * 4 + 2) * 136 + rsw] = f2bf(f.z);
                Vt[(c0 + i * 4 + 3) * 136 + rsw] = f2bf(f.w);
            }
            stage_mask_bits(Msb, mb, mi, bytemode, t, r0, j0);
        }
        __syncthreads();

        // S = Q·K^T  (scale already folded into Q)
        f32x4 sacc[8];
#pragma unroll
        for (int nt = 0; nt < 8; ++nt) sacc[nt] = (f32x4){0.f, 0.f, 0.f, 0.f};
#pragma unroll
        for (int ks = 0; ks < 2; ++ks) {
#pragma unroll
            for (int nt = 0; nt < 8; ++nt) {
                bfrag bk = *(const bfrag*)&KsPs[(nt * 16 + l16) * 72 + ks * 32 + quad * 8];
                sacc[nt] = __builtin_amdgcn_mfma_f32_16x16x32_bf16(qf[ks], bk, sacc[nt], 0, 0, 0);
            }
        }

        __syncthreads();  // K tile fully consumed by ALL waves; P may now overwrite it

        // exp + mask (register bit test), accumulate row sums, store P (bf16) wave-private
#pragma unroll
        for (int rg = 0; rg < 4; ++rg) {
            const int rloc = quad * 4 + rg;        // 0..15 within wave
            const unsigned* mrow = Msb[wv * 16 + rloc];
            unsigned s[4] = {mrow[0] >> l16, mrow[1] >> l16, mrow[2] >> l16, mrow[3] >> l16};
#pragma unroll
            for (int nt = 0; nt < 8; ++nt) {
                const unsigned bit = (s[nt >> 1] >> ((nt & 1) << 4)) & 1u;
                const float p = bit ? 0.f : __expf(sacc[nt][rg]);
                lsum[rg] += p;
                KsPs[psb + rloc * 136 + nt * 16 + l16] = f2bf(p);
            }
        }

        // O += P·V   (P is wave-private: in-wave lgkm ordering suffices)
#pragma unroll
        for (int ks = 0; ks < 4; ++ks) {
            bfrag ap = *(const bfrag*)&KsPs[psb + l16 * 136 + ks * 32 + quad * 8];
#pragma unroll
            for (int nt = 0; nt < 4; ++nt) {
                const int kss = ks ^ ((nt >> 1) & 1);  // undo V write swizzle (compile-time)
                bfrag bv2 = *(const bfrag*)&Vt[(nt * 16 + l16) * 136 + kss * 32 + quad * 8];
                acc_o[nt] = __builtin_amdgcn_mfma_f32_16x16x32_bf16(ap, bv2, acc_o[nt], 0, 0, 0);
            }
        }
    }

    // ---- finish row sums: reduce across the 16 column-lanes ----
    float linv[4];
#pragma unroll
    for (int rg = 0; rg < 4; ++rg) {
        float s2 = lsum[rg];
        s2 += __shfl_xor(s2, 1);
        s2 += __shfl_xor(s2, 2);
        s2 += __shfl_xor(s2, 4);
        s2 += __shfl_xor(s2, 8);
        linv[rg] = 1.f / s2;
    }

    // ---- write O = acc_o / l ----
#pragma unroll
    for (int nt = 0; nt < 4; ++nt) {
#pragma unroll
        for (int rg = 0; rg < 4; ++rg) {
            const int row = r0 + wv * 16 + quad * 4 + rg;
            out[((size_t)bh * S + row) * D + nt * 16 + l16] = acc_o[nt][rg] * linv[rg];
        }
    }

    // =================== Phase B: recompute S, write atten = P/l ===================
    float* Twv = reinterpret_cast<float*>(Vt) + wv * 1088;  // wave-private [16][68] f32
    for (int ch = 0; ch < NCH; ++ch) {
        const int j0 = ch * CHUNK;
        __syncthreads();
        {   // stage K + mask bits only
            const int r = t >> 1, c0 = (t & 1) * 32;
            const float* sk = &kb[(size_t)(j0 + r) * D + c0];
#pragma unroll
            for (int i = 0; i < 8; ++i) {
                float4 f = *(const float4*)&sk[i * 4];
                *(ushort4*)&KsPs[r * 72 + c0 + i * 4] = f2bf4(f);
            }
            stage_mask_bits(Msb, mb, mi, bytemode, t, r0, j0);
        }
        __syncthreads();

        f32x4 sacc[8];
#pragma unroll
        for (int nt = 0; nt < 8; ++nt) sacc[nt] = (f32x4){0.f, 0.f, 0.f, 0.f};
#pragma unroll
        for (int ks = 0; ks < 2; ++ks) {
#pragma unroll
            for (int nt = 0; nt < 8; ++nt) {
                bfrag bk = *(const bfrag*)&KsPs[(nt * 16 + l16) * 72 + ks * 32 + quad * 8];
                sacc[nt] = __builtin_amdgcn_mfma_f32_16x16x32_bf16(qf[ks], bk, sacc[nt], 0, 0, 0);
            }
        }

        // transpose through wave-private f32 buf -> float4 nontemporal stores
#pragma unroll
        for (int half = 0; half < 2; ++half) {
#pragma unroll
            for (int rg = 0; rg < 4; ++rg) {
                const int rloc = quad * 4 + rg;
                const unsigned* mrow = Msb[wv * 16 + rloc];
                unsigned s2[2] = {mrow[half * 2] >> l16, mrow[half * 2 + 1] >> l16};
#pragma unroll
                for (int ntl = 0; ntl < 4; ++ntl) {
                    const int nt = half * 4 + ntl;
                    const unsigned bit = (s2[ntl >> 1] >> ((ntl & 1) << 4)) & 1u;
                    const float val = bit ? 0.f : __expf(sacc[nt][rg]) * linv[rg];
                    Twv[rloc * 68 + ntl * 16 + l16] = val;
                }
            }
#pragma unroll
            for (int rr = 0; rr < 4; ++rr) {
                const int row = rr * 4 + quad;
                const f32x4 vals = *(const f32x4*)&Twv[row * 68 + l16 * 4];
                __builtin_nontemporal_store(
                    vals, (f32x4*)&atten[((size_t)bh * S + r0 + wv * 16 + row) * S +
                                         j0 + half * 64 + l16 * 4]);
            }
        }
    }
}

extern "C" void kernel_launch(void* const* d_in, const int* in_sizes, int n_in,
                              void* d_out, int out_size, void* d_ws, size_t ws_size,
                              hipStream_t stream) {
    const float* q = (const float*)d_in[0];
    const float* k = (const float*)d_in[1];
    const float* v = (const float*)d_in[2];
    const void* mask = d_in[3];
    float* out   = (float*)d_out;
    float* atten = out + (size_t)BH * S * D;  // outputs concatenated: out, atten
    int* flag = (int*)d_ws;

    mask_detect_kernel<<<1, 256, 0, stream>>>((const unsigned int*)mask, flag);

    dim3 grid(S / MTILE, BH);
    attn_mfma_kernel<<<grid, 256, 0, stream>>>(
        q, k, v, (const int*)mask, (const unsigned char*)mask, flag, out, atten);
}